// Round 7
// baseline (352.834 us; speedup 1.0000x reference)
//
#include <hip/hip_runtime.h>
#include <math.h>

// ---------------------------------------------------------------------------
// SimVQ forward, round 7: fix round-6's epilogue drain bug.
//  8-phase 256x256 coarse GEMM (T3+T4+T5), 512 thr / 8 waves, BK=64,
//  2 LDS K-tile buffers, K-half staging, counted vmcnt(4) in steady state.
//  BUG WAS: last tile (no prefetch) kept 4 loads in flight; vmcnt(4) was a
//  no-op, so its ks1 ds_reads raced the in-flight global_load_lds writes.
//  FIX: epilogue drain 4 -> 2 -> 0 (guide template's "drains 4→2→0").
// ---------------------------------------------------------------------------

typedef _Float16 f16;
typedef _Float16 f16x8 __attribute__((ext_vector_type(8)));
typedef _Float16 f16x4 __attribute__((ext_vector_type(4)));
typedef short s16x8 __attribute__((ext_vector_type(8)));
typedef float f32x4 __attribute__((ext_vector_type(4)));
typedef unsigned int u32;
typedef unsigned long long u64;
typedef unsigned short ushort_t;

#define INV2048 (1.0f/2048.0f)
#define MARGIN  0.010f

// ---- workspace layout (bytes) ----
#define OFF_Q    0u            // 16384*512*4 = 33554432
#define OFF_EHI  33554432u     // emb hi f16 (dead after codebook GEMM)
#define OFF_ELO  50331648u     // emb lo f16 (dead after codebook GEMM)
#define OFF_WHI  67108864u     // 512*512*2
#define OFF_WLO  67633152u
#define OFF_CB   68157440u     // codebook bf16 normalized, 16384*512*2
#define OFF_ZB   84934656u     // z normalized bf16, 8192*512*2
#define OFF_RL   93323264u     // 8192*4 per-row loss
#define OFF_PK   OFF_EHI       // alias: cand keys, 8192*256*8 = 16777216

__device__ __forceinline__ void gload_lds16(const void* g, void* l) {
  __builtin_amdgcn_global_load_lds(
      (const __attribute__((address_space(1))) u32*)g,
      (__attribute__((address_space(3))) u32*)l, 16, 0, 0);
}

// ---- u64 sort keys: high 32 = ordered float, low 32 = ~idx (tie->low idx) ----
__device__ __forceinline__ u64 make_key(float v, int idx) {
  u32 b = __float_as_uint(v);
  u32 m = (u32)((int)b >> 31) | 0x80000000u;
  return ((u64)(b ^ m) << 32) | (u32)(0x7FFFFFFF - idx);
}
__device__ __forceinline__ float key_val(u64 k) {
  u32 o = (u32)(k >> 32);
  u32 m = (o & 0x80000000u) ? 0x80000000u : 0xFFFFFFFFu;
  return __uint_as_float(o ^ m);   // key 0 -> NaN (always fails >= thresh)
}
__device__ __forceinline__ int key_idx(u64 k) {
  return 0x7FFFFFFF - (int)(u32)(k & 0xFFFFFFFFu);
}
__device__ __forceinline__ u64 umax64(u64 a, u64 b) { return a > b ? a : b; }

// ======================= exact fp16 hi/lo GEMM (codebook) ====================
// (unchanged — ~25us, not the bottleneck)
#define LDS_AHI 0
#define LDS_ALO 16384
#define LDS_BHI 32768
#define LDS_BLO 49152

// Stage 128 x 64 elems of 2-byte data (global row stride 1024B) into LDS.
__device__ __forceinline__ void stage_tile(const void* __restrict__ src, int row0,
                                           int kt, char* lds, int tid) {
#pragma unroll
  for (int i = 0; i < 4; ++i) {
    int lin = i * 256 + tid;
    int row = lin >> 3;
    int slot = lin & 7;
    int k8 = slot ^ (row & 7);
    const char* g = (const char*)src + (((size_t)(row0 + row)) << 10)
                    + (size_t)(kt * 128 + k8 * 16);
    gload_lds16(g, lds + lin * 16);
  }
}

__global__ __launch_bounds__(256, 2) void k_gemm_codebook(
    const f16* __restrict__ Ahi, const f16* __restrict__ Alo,
    const f16* __restrict__ Bhi, const f16* __restrict__ Blo,
    const float* __restrict__ bias, float* __restrict__ Q) {
  __shared__ __align__(16) char lds[65536];
  f32x4 hh[4][4], xx[4][4];
  const int tid = threadIdx.x;
  const int m0 = blockIdx.y * 128;
  const int n0 = blockIdx.x * 128;
  const int l = tid & 63;
  const int wid = tid >> 6;
  const int wr = (wid >> 1) * 64;
  const int wc = (wid & 1) * 64;
  const int r7 = (l & 15) & 7;

#pragma unroll
  for (int a = 0; a < 4; ++a)
#pragma unroll
    for (int b = 0; b < 4; ++b) {
      hh[a][b] = (f32x4){0.f, 0.f, 0.f, 0.f};
      xx[a][b] = (f32x4){0.f, 0.f, 0.f, 0.f};
    }

  for (int kt = 0; kt < 8; ++kt) {
    stage_tile(Ahi, m0, kt, lds + LDS_AHI, tid);
    stage_tile(Alo, m0, kt, lds + LDS_ALO, tid);
    stage_tile(Bhi, n0, kt, lds + LDS_BHI, tid);
    stage_tile(Blo, n0, kt, lds + LDS_BLO, tid);
    __syncthreads();
#pragma unroll
    for (int ks = 0; ks < 2; ++ks) {
      const int kg = ks * 4 + (l >> 4);
      const int s = (kg ^ r7) * 16;
      const char* pa = lds + (wr + (l & 15)) * 128 + s;
      const char* pb = lds + (wc + (l & 15)) * 128 + s;
      f16x8 ahi[4], alo[4];
#pragma unroll
      for (int mf = 0; mf < 4; ++mf) {
        ahi[mf] = *(const f16x8*)(pa + LDS_AHI + mf * 2048);
        alo[mf] = *(const f16x8*)(pa + LDS_ALO + mf * 2048);
      }
#pragma unroll
      for (int nf = 0; nf < 4; ++nf) {
        f16x8 bhi = *(const f16x8*)(pb + LDS_BHI + nf * 2048);
        f16x8 blo = *(const f16x8*)(pb + LDS_BLO + nf * 2048);
#pragma unroll
        for (int mf = 0; mf < 4; ++mf) {
          hh[mf][nf] = __builtin_amdgcn_mfma_f32_16x16x32_f16(ahi[mf], bhi, hh[mf][nf], 0, 0, 0);
          xx[mf][nf] = __builtin_amdgcn_mfma_f32_16x16x32_f16(ahi[mf], blo, xx[mf][nf], 0, 0, 0);
          xx[mf][nf] = __builtin_amdgcn_mfma_f32_16x16x32_f16(alo[mf], bhi, xx[mf][nf], 0, 0, 0);
        }
      }
    }
    __syncthreads();
  }

#pragma unroll
  for (int mf = 0; mf < 4; ++mf)
#pragma unroll
    for (int nf = 0; nf < 4; ++nf)
#pragma unroll
      for (int j = 0; j < 4; ++j) {
        int row = m0 + wr + mf * 16 + (l >> 4) * 4 + j;
        int col = n0 + wc + nf * 16 + (l & 15);
        Q[(size_t)row * 512 + col] = hh[mf][nf][j] + xx[mf][nf][j] * INV2048 + bias[col];
      }
}

// ================= 8-phase 256x256 bf16 coarse GEMM + epilogue ===============
// A = codebook bf16 [16384][512], B = z_n bf16 [8192][512]. C[code][z].
// LDS per buffer: A ks-planes @0,16384; B ks-planes @32768,49152.
// Plane layout K-major: chunk(kg,row) at kg*4096 + row*16.
// WN = vmcnt wait count for this phase (4 steady; last tile 2,0,0,0).
#define PHASE(CUR, KS, MFH, PF, STISA, STKS, WN)                               \
  {                                                                            \
    const char* base_ = lds + (CUR) * 65536 + (KS) * 16384;                    \
    if ((MFH) == 0) {                                                          \
      bfr[0] = *(const s16x8*)(base_ + boff + 0);                              \
      bfr[1] = *(const s16x8*)(base_ + boff + 256);                            \
      bfr[2] = *(const s16x8*)(base_ + boff + 512);                            \
      bfr[3] = *(const s16x8*)(base_ + boff + 768);                            \
    }                                                                          \
    s16x8 af0 = *(const s16x8*)(base_ + aoff + (MFH) * 1024 + 0);              \
    s16x8 af1 = *(const s16x8*)(base_ + aoff + (MFH) * 1024 + 256);            \
    s16x8 af2 = *(const s16x8*)(base_ + aoff + (MFH) * 1024 + 512);            \
    s16x8 af3 = *(const s16x8*)(base_ + aoff + (MFH) * 1024 + 768);            \
    if (PF) {                                                                  \
      char* d_ = lds + ((t & 1) ^ 1) * 65536 + ((STISA) ? 0 : 32768)           \
                 + (STKS) * 16384 + tid * 16;                                  \
      const char* g_ = ((STISA) ? srcA : srcB) + (t + 1) * 128 + (STKS) * 64;  \
      gload_lds16(g_, d_);                                                     \
      gload_lds16(g_ + 32, d_ + 8192);                                         \
    }                                                                          \
    __builtin_amdgcn_s_setprio(1);                                             \
    _Pragma("unroll") for (int nf = 0; nf < 4; ++nf) {                         \
      acc[(MFH)*4+0][nf] = __builtin_amdgcn_mfma_f32_16x16x32_bf16(af0, bfr[nf], acc[(MFH)*4+0][nf], 0, 0, 0); \
      acc[(MFH)*4+1][nf] = __builtin_amdgcn_mfma_f32_16x16x32_bf16(af1, bfr[nf], acc[(MFH)*4+1][nf], 0, 0, 0); \
      acc[(MFH)*4+2][nf] = __builtin_amdgcn_mfma_f32_16x16x32_bf16(af2, bfr[nf], acc[(MFH)*4+2][nf], 0, 0, 0); \
      acc[(MFH)*4+3][nf] = __builtin_amdgcn_mfma_f32_16x16x32_bf16(af3, bfr[nf], acc[(MFH)*4+3][nf], 0, 0, 0); \
    }                                                                          \
    __builtin_amdgcn_s_setprio(0);                                             \
    asm volatile("s_waitcnt vmcnt(" #WN ")\n\ts_barrier" ::: "memory");        \
  }

__global__ __launch_bounds__(512, 2) void k_gemm_coarse8(
    const ushort_t* __restrict__ CB, const ushort_t* __restrict__ ZB,
    u64* __restrict__ pk) {
  __shared__ __align__(16) char lds[131072];
  const int tid = threadIdx.x;
  const int l = tid & 63;
  const int wid = tid >> 6;
  const int wr = wid >> 2;        // 0..1: code half (128 rows)
  const int wc = wid & 3;         // 0..3: z quarter (64 cols)
  const int cb0 = blockIdx.x * 256;   // code chunk base
  const int zb0 = blockIdx.y * 256;   // z base

  // staging source: thread stages chunks (kg=skg,row) and (kg=skg+2,row)
  const int srow = tid & 255, skg = tid >> 8;
  const char* srcA = (const char*)CB + (((size_t)(cb0 + srow)) << 10) + skg * 16;
  const char* srcB = (const char*)ZB + (((size_t)(zb0 + srow)) << 10) + skg * 16;

  // frag read offsets (K-major plane: kg*4096 + row*16)
  const int lane_off = (l >> 4) * 4096 + (l & 15) * 16;
  const int aoff = wr * 2048 + lane_off;            // + MFH*1024 + mfi*256
  const int boff = 32768 + wc * 1024 + lane_off;    // + nf*256

  f32x4 acc[8][4];
#pragma unroll
  for (int a = 0; a < 8; ++a)
#pragma unroll
    for (int b = 0; b < 4; ++b) acc[a][b] = (f32x4){0.f, 0.f, 0.f, 0.f};

  // prologue: stage tile 0 halves in slot order A0,B0,A1,B1
  {
    char* d;
    const char* g;
    d = lds + 0 + tid * 16;        g = srcA + 0;         gload_lds16(g, d); gload_lds16(g + 32, d + 8192);
    d = lds + 32768 + tid * 16;    g = srcB + 0;         gload_lds16(g, d); gload_lds16(g + 32, d + 8192);
    d = lds + 16384 + tid * 16;    g = srcA + 64;        gload_lds16(g, d); gload_lds16(g + 32, d + 8192);
    d = lds + 49152 + tid * 16;    g = srcB + 64;        gload_lds16(g, d); gload_lds16(g + 32, d + 8192);
    asm volatile("s_waitcnt vmcnt(4)\n\ts_barrier" ::: "memory");
  }

  s16x8 bfr[4];
  for (int t = 0; t < 7; ++t) {    // steady state: stages tile t+1
    const int cur = t & 1;
    PHASE(cur, 0, 0, true, 1, 0, 4)   // reads ks0 B+A(mf0-3); stages A-ks0(t+1)
    PHASE(cur, 0, 1, true, 0, 0, 4)   // reads ks0 A(mf4-7);   stages B-ks0(t+1)
    PHASE(cur, 1, 0, true, 1, 1, 4)   // reads ks1 B+A(mf0-3); stages A-ks1(t+1)
    PHASE(cur, 1, 1, true, 0, 1, 4)   // reads ks1 A(mf4-7);   stages B-ks1(t+1)
  }
  {
    // last tile: no prefetch. Queue holds [A1_7, B1_7] (4 loads).
    // Drain 4 -> 2 -> 0 so the ks1 reads in P3/P4 see completed LDS writes.
    const int t = 7;
    (void)t;
    PHASE(1, 0, 0, false, 1, 0, 2)    // drains A1_7
    PHASE(1, 0, 1, false, 0, 0, 0)    // drains B1_7
    PHASE(1, 1, 0, false, 1, 1, 0)    // reads ks1: now safe
    PHASE(1, 1, 1, false, 0, 1, 0)
  }

  // ---- epilogue: chunk-max + within-margin collect over 256 codes ----
  // lane l holds, per nf: z-col wc*64+nf*16+(l&15); codes cb0 + wr*128 +
  // mfall*16 + (l>>4)*4 + j  (mfall 0..7, j 0..3).
  float* cmax = (float*)lds;            // [256 cols][2 wr]
  u32* cnt = (u32*)(lds + 2048);        // [256]
  u64* slots = (u64*)(lds + 4096);      // [256][4]

  float cm[4];
#pragma unroll
  for (int nf = 0; nf < 4; ++nf) {
    float m = acc[0][nf][0];
#pragma unroll
    for (int mfa = 0; mfa < 8; ++mfa)
#pragma unroll
      for (int j = 0; j < 4; ++j) m = fmaxf(m, acc[mfa][nf][j]);
    m = fmaxf(m, __shfl_xor(m, 16, 64));
    m = fmaxf(m, __shfl_xor(m, 32, 64));
    cm[nf] = m;
  }
  if (tid < 256) cnt[tid] = 0;
  slots[tid] = 0;
  slots[tid + 512] = 0;
  if ((l >> 4) == 0) {
#pragma unroll
    for (int nf = 0; nf < 4; ++nf)
      cmax[(wc * 64 + nf * 16 + l) * 2 + wr] = cm[nf];
  }
  __syncthreads();

#pragma unroll
  for (int nf = 0; nf < 4; ++nf) {
    int col = wc * 64 + nf * 16 + (l & 15);
    float thresh = fmaxf(cmax[col * 2], cmax[col * 2 + 1]) - MARGIN;
#pragma unroll
    for (int mfa = 0; mfa < 8; ++mfa)
#pragma unroll
      for (int j = 0; j < 4; ++j) {
        float v = acc[mfa][nf][j];
        if (v >= thresh) {
          int code = cb0 + wr * 128 + mfa * 16 + ((l >> 4) << 2) + j;
          u32 p = atomicAdd(&cnt[col], 1u);
          if (p < 4) slots[col * 4 + p] = make_key(v, code);
        }
      }
  }
  __syncthreads();

  if (tid < 256) {
    size_t base = (((size_t)(zb0 + tid)) * 64 + blockIdx.x) * 4;
#pragma unroll
    for (int s = 0; s < 4; ++s) pk[base + s] = slots[tid * 4 + s];
  }
}

// ---- f32 -> fp16 hi/lo split ----
__global__ __launch_bounds__(256) void k_split(const float* __restrict__ src,
                                               f16* __restrict__ hi,
                                               f16* __restrict__ lo, int n4) {
  int i = blockIdx.x * 256 + threadIdx.x;
  if (i >= n4) return;
  const float4 v = ((const float4*)src)[i];
  f16 h0 = (f16)v.x, h1 = (f16)v.y, h2 = (f16)v.z, h3 = (f16)v.w;
  ((f16x4*)hi)[i] = (f16x4){h0, h1, h2, h3};
  ((f16x4*)lo)[i] = (f16x4){(f16)((v.x - (float)h0) * 2048.0f),
                            (f16)((v.y - (float)h1) * 2048.0f),
                            (f16)((v.z - (float)h2) * 2048.0f),
                            (f16)((v.w - (float)h3) * 2048.0f)};
}

__device__ __forceinline__ ushort_t f2bf_rne(float f) {
  u32 b = __float_as_uint(f);
  b += 0x7FFFu + ((b >> 16) & 1u);
  return (ushort_t)(b >> 16);
}

// ---- row L2-normalize src -> bf16 dst. One block per row, 512 cols ----
__global__ __launch_bounds__(256) void k_norm_bf16(const float* __restrict__ src,
                                                   ushort_t* __restrict__ dst) {
  __shared__ float red[256];
  const int row = blockIdx.x, t = threadIdx.x;
  float q0 = src[(size_t)row * 512 + t];
  float q1 = src[(size_t)row * 512 + t + 256];
  red[t] = q0 * q0 + q1 * q1;
  __syncthreads();
  for (int s = 128; s > 0; s >>= 1) {
    if (t < s) red[t] += red[t + s];
    __syncthreads();
  }
  float inv = 1.0f / fmaxf(sqrtf(red[0]), 1e-12f);
  dst[(size_t)row * 512 + t] = f2bf_rne(q0 * inv);
  dst[(size_t)row * 512 + t + 256] = f2bf_rne(q1 * inv);
}

// ---- candidate rescore (f64) + gather + straight-through + row loss ----
__global__ __launch_bounds__(256) void k_rescore_gather(
    const u64* __restrict__ pk, const float* __restrict__ Q,
    const float* __restrict__ z, float* __restrict__ outq,
    float* __restrict__ outidx, float* __restrict__ rloss) {
  __shared__ float sz[512];
  __shared__ double redd[8];
  __shared__ u64 redk[4];
  __shared__ int cand[64];
  __shared__ int ccount;
  const int row = blockIdx.x, t = threadIdx.x;

  sz[t] = z[(size_t)row * 512 + t];
  sz[t + 256] = z[(size_t)row * 512 + t + 256];
  if (t == 0) ccount = 0;

  u64 k1 = pk[(size_t)row * 256 + t];   // 64 chunks x 4 slots = 256 keys/row
  u64 km = k1;
  for (int m = 1; m < 64; m <<= 1)
    km = umax64(km, (u64)__shfl_xor((long long)km, m));
  if ((t & 63) == 0) redk[t >> 6] = km;
  __syncthreads();
  u64 gk = umax64(umax64(redk[0], redk[1]), umax64(redk[2], redk[3]));
  float thresh = key_val(gk) - MARGIN;

  if (key_val(k1) >= thresh) { int p = atomicAdd(&ccount, 1); if (p < 64) cand[p] = key_idx(k1); }
  __syncthreads();
  int nc = ccount < 64 ? ccount : 64;

  double bs = -1e300;
  int bi = 0x7FFFFFFF;
  for (int c = 0; c < nc; ++c) {
    int code = cand[c];
    const float* Qr = Q + (size_t)code * 512;
    double dotp = 0.0, qq = 0.0;
#pragma unroll
    for (int h = 0; h < 2; ++h) {
      int d = t + h * 256;
      double qv = (double)Qr[d];
      dotp += (double)sz[d] * qv;
      qq += qv * qv;
    }
    for (int m = 1; m < 64; m <<= 1) {
      dotp += __shfl_xor(dotp, m);
      qq += __shfl_xor(qq, m);
    }
    if ((t & 63) == 0) { redd[t >> 6] = dotp; redd[4 + (t >> 6)] = qq; }
    __syncthreads();
    double dsum = redd[0] + redd[1] + redd[2] + redd[3];
    double qsum = redd[4] + redd[5] + redd[6] + redd[7];
    double s = dsum / fmax(sqrt(qsum), 1e-12);
    if (s > bs || (s == bs && code < bi)) { bs = s; bi = code; }
    __syncthreads();
  }

  const float* Qb = Q + (size_t)bi * 512;
  double lsum = 0.0;
#pragma unroll
  for (int h = 0; h < 2; ++h) {
    int d = t + h * 256;
    float qv = Qb[d], zv = sz[d];
    outq[(size_t)row * 512 + d] = zv + (qv - zv);
    float df = qv - zv;
    lsum += (double)df * (double)df;
  }
  for (int m = 1; m < 64; m <<= 1) lsum += __shfl_xor(lsum, m);
  if ((t & 63) == 0) redd[t >> 6] = lsum;
  __syncthreads();
  if (t == 0) {
    rloss[row] = (float)(redd[0] + redd[1] + redd[2] + redd[3]);
    outidx[row] = (float)bi;
  }
}

__global__ __launch_bounds__(256) void k_loss_final(const float* __restrict__ rloss,
                                                    float* __restrict__ out_loss) {
  __shared__ float sl[256];
  int t = threadIdx.x;
  float s = 0.f;
#pragma unroll
  for (int i = 0; i < 32; ++i) s += rloss[t + i * 256];
  sl[t] = s;
  __syncthreads();
  for (int k = 128; k > 0; k >>= 1) {
    if (t < k) sl[t] += sl[t + k];
    __syncthreads();
  }
  if (t == 0) out_loss[0] = 1.25f * sl[0] / 4194304.0f;
}

extern "C" void kernel_launch(void* const* d_in, const int* in_sizes, int n_in,
                              void* d_out, int out_size, void* d_ws, size_t ws_size,
                              hipStream_t stream) {
  const float* z = (const float*)d_in[0];
  const float* emb = (const float*)d_in[1];
  const float* pw = (const float*)d_in[2];
  const float* pb = (const float*)d_in[3];

  char* ws = (char*)d_ws;
  float* Q = (float*)(ws + OFF_Q);
  f16* ehi = (f16*)(ws + OFF_EHI);
  f16* elo = (f16*)(ws + OFF_ELO);
  f16* whi = (f16*)(ws + OFF_WHI);
  f16* wlo = (f16*)(ws + OFF_WLO);
  ushort_t* cb = (ushort_t*)(ws + OFF_CB);
  ushort_t* zb = (ushort_t*)(ws + OFF_ZB);
  u64* pk = (u64*)(ws + OFF_PK);
  float* rloss = (float*)(ws + OFF_RL);

  float* outq = (float*)d_out;
  float* outloss = outq + 4194304;
  float* outidx = outq + 4194305;

  k_split<<<8192, 256, 0, stream>>>(emb, ehi, elo, 2097152);
  k_split<<<256, 256, 0, stream>>>(pw, whi, wlo, 65536);
  k_norm_bf16<<<8192, 256, 0, stream>>>(z, zb);                    // z_n bf16
  k_gemm_codebook<<<dim3(4, 128), 256, 0, stream>>>(ehi, elo, whi, wlo, pb, Q);
  k_norm_bf16<<<16384, 256, 0, stream>>>(Q, cb);                   // c_n bf16
  k_gemm_coarse8<<<dim3(64, 32), 512, 0, stream>>>(cb, zb, pk);
  k_rescore_gather<<<8192, 256, 0, stream>>>(pk, Q, z, outq, outidx, rloss);
  k_loss_final<<<1, 256, 0, stream>>>(rloss, outloss);
}

// Round 8
// 300.550 us; speedup vs baseline: 1.1740x; 1.1740x over previous
//
#include <hip/hip_runtime.h>
#include <math.h>

// ---------------------------------------------------------------------------
// SimVQ forward, round 8: fix the 8-phase schedule's two stalls.
//  (a) LDS back to row-major + (row&7) XOR swizzle -> coalesced staging
//      (8 lanes/row) and the proven frag-read pattern.
//  (b) stage ALL 8 loads (A+B of tile t+1) at phase 1; waits only at
//      end-ph3 vmcnt(4) and end-ph4 vmcnt(0): ~2.5-3.5 phases of latency
//      cover vs round 7's 1.5. Last tile stages nothing -> waits are no-ops.
// ---------------------------------------------------------------------------

typedef _Float16 f16;
typedef _Float16 f16x8 __attribute__((ext_vector_type(8)));
typedef _Float16 f16x4 __attribute__((ext_vector_type(4)));
typedef short s16x8 __attribute__((ext_vector_type(8)));
typedef float f32x4 __attribute__((ext_vector_type(4)));
typedef unsigned int u32;
typedef unsigned long long u64;
typedef unsigned short ushort_t;

#define INV2048 (1.0f/2048.0f)
#define MARGIN  0.010f

// ---- workspace layout (bytes) ----
#define OFF_Q    0u            // 16384*512*4 = 33554432
#define OFF_EHI  33554432u     // emb hi f16 (dead after codebook GEMM)
#define OFF_ELO  50331648u     // emb lo f16 (dead after codebook GEMM)
#define OFF_WHI  67108864u     // 512*512*2
#define OFF_WLO  67633152u
#define OFF_CB   68157440u     // codebook bf16 normalized, 16384*512*2
#define OFF_ZB   84934656u     // z normalized bf16, 8192*512*2
#define OFF_RL   93323264u     // 8192*4 per-row loss
#define OFF_PK   OFF_EHI       // alias: cand keys, 8192*256*8 = 16777216

__device__ __forceinline__ void gload_lds16(const void* g, void* l) {
  __builtin_amdgcn_global_load_lds(
      (const __attribute__((address_space(1))) u32*)g,
      (__attribute__((address_space(3))) u32*)l, 16, 0, 0);
}

// ---- u64 sort keys: high 32 = ordered float, low 32 = ~idx (tie->low idx) ----
__device__ __forceinline__ u64 make_key(float v, int idx) {
  u32 b = __float_as_uint(v);
  u32 m = (u32)((int)b >> 31) | 0x80000000u;
  return ((u64)(b ^ m) << 32) | (u32)(0x7FFFFFFF - idx);
}
__device__ __forceinline__ float key_val(u64 k) {
  u32 o = (u32)(k >> 32);
  u32 m = (o & 0x80000000u) ? 0x80000000u : 0xFFFFFFFFu;
  return __uint_as_float(o ^ m);   // key 0 -> NaN (always fails >= thresh)
}
__device__ __forceinline__ int key_idx(u64 k) {
  return 0x7FFFFFFF - (int)(u32)(k & 0xFFFFFFFFu);
}
__device__ __forceinline__ u64 umax64(u64 a, u64 b) { return a > b ? a : b; }

// ======================= exact fp16 hi/lo GEMM (codebook) ====================
// (unchanged — ~25us, not the bottleneck)
#define LDS_AHI 0
#define LDS_ALO 16384
#define LDS_BHI 32768
#define LDS_BLO 49152

// Stage 128 x 64 elems of 2-byte data (global row stride 1024B) into LDS.
__device__ __forceinline__ void stage_tile(const void* __restrict__ src, int row0,
                                           int kt, char* lds, int tid) {
#pragma unroll
  for (int i = 0; i < 4; ++i) {
    int lin = i * 256 + tid;
    int row = lin >> 3;
    int slot = lin & 7;
    int k8 = slot ^ (row & 7);
    const char* g = (const char*)src + (((size_t)(row0 + row)) << 10)
                    + (size_t)(kt * 128 + k8 * 16);
    gload_lds16(g, lds + lin * 16);
  }
}

__global__ __launch_bounds__(256, 2) void k_gemm_codebook(
    const f16* __restrict__ Ahi, const f16* __restrict__ Alo,
    const f16* __restrict__ Bhi, const f16* __restrict__ Blo,
    const float* __restrict__ bias, float* __restrict__ Q) {
  __shared__ __align__(16) char lds[65536];
  f32x4 hh[4][4], xx[4][4];
  const int tid = threadIdx.x;
  const int m0 = blockIdx.y * 128;
  const int n0 = blockIdx.x * 128;
  const int l = tid & 63;
  const int wid = tid >> 6;
  const int wr = (wid >> 1) * 64;
  const int wc = (wid & 1) * 64;
  const int r7 = (l & 15) & 7;

#pragma unroll
  for (int a = 0; a < 4; ++a)
#pragma unroll
    for (int b = 0; b < 4; ++b) {
      hh[a][b] = (f32x4){0.f, 0.f, 0.f, 0.f};
      xx[a][b] = (f32x4){0.f, 0.f, 0.f, 0.f};
    }

  for (int kt = 0; kt < 8; ++kt) {
    stage_tile(Ahi, m0, kt, lds + LDS_AHI, tid);
    stage_tile(Alo, m0, kt, lds + LDS_ALO, tid);
    stage_tile(Bhi, n0, kt, lds + LDS_BHI, tid);
    stage_tile(Blo, n0, kt, lds + LDS_BLO, tid);
    __syncthreads();
#pragma unroll
    for (int ks = 0; ks < 2; ++ks) {
      const int kg = ks * 4 + (l >> 4);
      const int s = (kg ^ r7) * 16;
      const char* pa = lds + (wr + (l & 15)) * 128 + s;
      const char* pb = lds + (wc + (l & 15)) * 128 + s;
      f16x8 ahi[4], alo[4];
#pragma unroll
      for (int mf = 0; mf < 4; ++mf) {
        ahi[mf] = *(const f16x8*)(pa + LDS_AHI + mf * 2048);
        alo[mf] = *(const f16x8*)(pa + LDS_ALO + mf * 2048);
      }
#pragma unroll
      for (int nf = 0; nf < 4; ++nf) {
        f16x8 bhi = *(const f16x8*)(pb + LDS_BHI + nf * 2048);
        f16x8 blo = *(const f16x8*)(pb + LDS_BLO + nf * 2048);
#pragma unroll
        for (int mf = 0; mf < 4; ++mf) {
          hh[mf][nf] = __builtin_amdgcn_mfma_f32_16x16x32_f16(ahi[mf], bhi, hh[mf][nf], 0, 0, 0);
          xx[mf][nf] = __builtin_amdgcn_mfma_f32_16x16x32_f16(ahi[mf], blo, xx[mf][nf], 0, 0, 0);
          xx[mf][nf] = __builtin_amdgcn_mfma_f32_16x16x32_f16(alo[mf], bhi, xx[mf][nf], 0, 0, 0);
        }
      }
    }
    __syncthreads();
  }

#pragma unroll
  for (int mf = 0; mf < 4; ++mf)
#pragma unroll
    for (int nf = 0; nf < 4; ++nf)
#pragma unroll
      for (int j = 0; j < 4; ++j) {
        int row = m0 + wr + mf * 16 + (l >> 4) * 4 + j;
        int col = n0 + wc + nf * 16 + (l & 15);
        Q[(size_t)row * 512 + col] = hh[mf][nf][j] + xx[mf][nf][j] * INV2048 + bias[col];
      }
}

// ================= 8-phase 256x256 bf16 coarse GEMM + epilogue ===============
// A = codebook bf16 [16384][512], B = z_n bf16 [8192][512]. C[code][z].
// LDS: buf c at c*65536: A = 256 rows x 128B @+0, B = 256 rows x 128B @+32768.
// Row layout: physical slot s of row r holds logical k-chunk (s ^ (r&7)).
// Phase sync: raw s_barrier at ph1/ph2; vmcnt(4)+bar at ph3; vmcnt(0)+bar
// at ph4 (tile boundary). All 8 staging loads issue at ph1.
#define BAR() __builtin_amdgcn_s_barrier()

#define PHASE(CUR, KS, MFH, PF, SYNC)                                          \
  {                                                                            \
    const char* abase_ = lds + (CUR) * 65536;                                  \
    if ((MFH) == 0) {                                                          \
      const char* pb_ = abase_ + 32768 + boff + ((KS) ? s1 : s0);              \
      bfr[0] = *(const s16x8*)(pb_ + 0);                                       \
      bfr[1] = *(const s16x8*)(pb_ + 2048);                                    \
      bfr[2] = *(const s16x8*)(pb_ + 4096);                                    \
      bfr[3] = *(const s16x8*)(pb_ + 6144);                                    \
    }                                                                          \
    const char* pa_ = abase_ + aoff + (MFH) * 8192 + ((KS) ? s1 : s0);         \
    s16x8 af0 = *(const s16x8*)(pa_ + 0);                                      \
    s16x8 af1 = *(const s16x8*)(pa_ + 2048);                                   \
    s16x8 af2 = *(const s16x8*)(pa_ + 4096);                                   \
    s16x8 af3 = *(const s16x8*)(pa_ + 6144);                                   \
    if (PF) { /* stage tile t+1 (A then B) into buf CUR^1, coalesced */        \
      char* dA_ = lds + ((CUR) ^ 1) * 65536 + tid * 16;                        \
      const char* gA_ = srcA + (t + 1) * 128;                                  \
      gload_lds16(gA_, dA_);                                                   \
      gload_lds16(gA_ + 65536, dA_ + 8192);                                    \
      gload_lds16(gA_ + 131072, dA_ + 16384);                                  \
      gload_lds16(gA_ + 196608, dA_ + 24576);                                  \
      char* dB_ = dA_ + 32768;                                                 \
      const char* gB_ = srcB + (t + 1) * 128;                                  \
      gload_lds16(gB_, dB_);                                                   \
      gload_lds16(gB_ + 65536, dB_ + 8192);                                    \
      gload_lds16(gB_ + 131072, dB_ + 16384);                                  \
      gload_lds16(gB_ + 196608, dB_ + 24576);                                  \
    }                                                                          \
    __builtin_amdgcn_s_setprio(1);                                             \
    _Pragma("unroll") for (int nf = 0; nf < 4; ++nf) {                         \
      acc[(MFH)*4+0][nf] = __builtin_amdgcn_mfma_f32_16x16x32_bf16(af0, bfr[nf], acc[(MFH)*4+0][nf], 0, 0, 0); \
      acc[(MFH)*4+1][nf] = __builtin_amdgcn_mfma_f32_16x16x32_bf16(af1, bfr[nf], acc[(MFH)*4+1][nf], 0, 0, 0); \
      acc[(MFH)*4+2][nf] = __builtin_amdgcn_mfma_f32_16x16x32_bf16(af2, bfr[nf], acc[(MFH)*4+2][nf], 0, 0, 0); \
      acc[(MFH)*4+3][nf] = __builtin_amdgcn_mfma_f32_16x16x32_bf16(af3, bfr[nf], acc[(MFH)*4+3][nf], 0, 0, 0); \
    }                                                                          \
    __builtin_amdgcn_s_setprio(0);                                             \
    SYNC;                                                                      \
  }

__global__ __launch_bounds__(512, 2) void k_gemm_coarse8(
    const ushort_t* __restrict__ CB, const ushort_t* __restrict__ ZB,
    u64* __restrict__ pk) {
  __shared__ __align__(16) char lds[131072];
  const int tid = threadIdx.x;
  const int l = tid & 63;
  const int wid = tid >> 6;
  const int wr = wid >> 2;        // 0..1: code half (128 rows)
  const int wc = wid & 3;         // 0..3: z quarter (64 cols)
  const int cb0 = blockIdx.x * 256;   // code chunk base
  const int zb0 = blockIdx.y * 256;   // z base

  // staging: thread handles rows {(tid>>3) + i*64}, slot tid&7 of each row.
  // XOR applied on the GLOBAL source column (both-sides rule); LDS dest linear.
  const int k8 = (tid & 7) ^ ((tid >> 3) & 7);
  const char* srcA = (const char*)CB + (((size_t)(cb0 + (tid >> 3))) << 10) + k8 * 16;
  const char* srcB = (const char*)ZB + (((size_t)(zb0 + (tid >> 3))) << 10) + k8 * 16;

  // frag read offsets (row-major, 128B rows, slot = (kg ^ r7))
  const int r7 = (l & 15) & 7;
  const int s0 = (((l >> 4)) ^ r7) * 16;        // ks0 slot byte
  const int s1 = (((l >> 4) | 4) ^ r7) * 16;    // ks1 slot byte
  const int aoff = wr * 16384 + (l & 15) * 128; // + MFH*8192 + mfi*2048
  const int boff = wc * 8192 + (l & 15) * 128;  // + nf*2048 (B region +32768)

  f32x4 acc[8][4];
#pragma unroll
  for (int a = 0; a < 8; ++a)
#pragma unroll
    for (int b = 0; b < 4; ++b) acc[a][b] = (f32x4){0.f, 0.f, 0.f, 0.f};

  // prologue: stage tile 0 into buf0, full drain
  {
    char* dA_ = lds + tid * 16;
    gload_lds16(srcA, dA_);
    gload_lds16(srcA + 65536, dA_ + 8192);
    gload_lds16(srcA + 131072, dA_ + 16384);
    gload_lds16(srcA + 196608, dA_ + 24576);
    char* dB_ = dA_ + 32768;
    gload_lds16(srcB, dB_);
    gload_lds16(srcB + 65536, dB_ + 8192);
    gload_lds16(srcB + 131072, dB_ + 16384);
    gload_lds16(srcB + 196608, dB_ + 24576);
    asm volatile("s_waitcnt vmcnt(0)" ::: "memory");
    BAR();
  }

  s16x8 bfr[4];
#pragma unroll
  for (int t = 0; t < 8; ++t) {
    const int cur = t & 1;
    const bool pf = (t < 7);
    PHASE(cur, 0, 0, pf, BAR())                                            // ks0, A mf0-3 (+8 stages)
    PHASE(cur, 0, 1, false, BAR())                                         // ks0, A mf4-7
    PHASE(cur, 1, 0, false, { asm volatile("s_waitcnt vmcnt(4)" ::: "memory"); BAR(); })  // retires A(t+1)
    PHASE(cur, 1, 1, false, { asm volatile("s_waitcnt vmcnt(0)" ::: "memory"); BAR(); })  // retires B(t+1)
  }

  // ---- epilogue: chunk-max + within-margin collect over 256 codes ----
  // lane l holds, per nf: z-col wc*64+nf*16+(l&15); codes cb0 + wr*128 +
  // mfa*16 + (l>>4)*4 + j  (mfa 0..7, j 0..3).
  float* cmax = (float*)lds;            // [256 cols][2 wr]
  u32* cnt = (u32*)(lds + 2048);        // [256]
  u64* slots = (u64*)(lds + 4096);      // [256][4]

  float cm[4];
#pragma unroll
  for (int nf = 0; nf < 4; ++nf) {
    float m = acc[0][nf][0];
#pragma unroll
    for (int mfa = 0; mfa < 8; ++mfa)
#pragma unroll
      for (int j = 0; j < 4; ++j) m = fmaxf(m, acc[mfa][nf][j]);
    m = fmaxf(m, __shfl_xor(m, 16, 64));
    m = fmaxf(m, __shfl_xor(m, 32, 64));
    cm[nf] = m;
  }
  if (tid < 256) cnt[tid] = 0;
  slots[tid] = 0;
  slots[tid + 512] = 0;
  if ((l >> 4) == 0) {
#pragma unroll
    for (int nf = 0; nf < 4; ++nf)
      cmax[(wc * 64 + nf * 16 + l) * 2 + wr] = cm[nf];
  }
  __syncthreads();

#pragma unroll
  for (int nf = 0; nf < 4; ++nf) {
    int col = wc * 64 + nf * 16 + (l & 15);
    float thresh = fmaxf(cmax[col * 2], cmax[col * 2 + 1]) - MARGIN;
#pragma unroll
    for (int mfa = 0; mfa < 8; ++mfa)
#pragma unroll
      for (int j = 0; j < 4; ++j) {
        float v = acc[mfa][nf][j];
        if (v >= thresh) {
          int code = cb0 + wr * 128 + mfa * 16 + ((l >> 4) << 2) + j;
          u32 p = atomicAdd(&cnt[col], 1u);
          if (p < 4) slots[col * 4 + p] = make_key(v, code);
        }
      }
  }
  __syncthreads();

  if (tid < 256) {
    size_t base = (((size_t)(zb0 + tid)) * 64 + blockIdx.x) * 4;
#pragma unroll
    for (int s = 0; s < 4; ++s) pk[base + s] = slots[tid * 4 + s];
  }
}

// ---- f32 -> fp16 hi/lo split ----
__global__ __launch_bounds__(256) void k_split(const float* __restrict__ src,
                                               f16* __restrict__ hi,
                                               f16* __restrict__ lo, int n4) {
  int i = blockIdx.x * 256 + threadIdx.x;
  if (i >= n4) return;
  const float4 v = ((const float4*)src)[i];
  f16 h0 = (f16)v.x, h1 = (f16)v.y, h2 = (f16)v.z, h3 = (f16)v.w;
  ((f16x4*)hi)[i] = (f16x4){h0, h1, h2, h3};
  ((f16x4*)lo)[i] = (f16x4){(f16)((v.x - (float)h0) * 2048.0f),
                            (f16)((v.y - (float)h1) * 2048.0f),
                            (f16)((v.z - (float)h2) * 2048.0f),
                            (f16)((v.w - (float)h3) * 2048.0f)};
}

__device__ __forceinline__ ushort_t f2bf_rne(float f) {
  u32 b = __float_as_uint(f);
  b += 0x7FFFu + ((b >> 16) & 1u);
  return (ushort_t)(b >> 16);
}

// ---- row L2-normalize src -> bf16 dst. One block per row, 512 cols ----
__global__ __launch_bounds__(256) void k_norm_bf16(const float* __restrict__ src,
                                                   ushort_t* __restrict__ dst) {
  __shared__ float red[256];
  const int row = blockIdx.x, t = threadIdx.x;
  float q0 = src[(size_t)row * 512 + t];
  float q1 = src[(size_t)row * 512 + t + 256];
  red[t] = q0 * q0 + q1 * q1;
  __syncthreads();
  for (int s = 128; s > 0; s >>= 1) {
    if (t < s) red[t] += red[t + s];
    __syncthreads();
  }
  float inv = 1.0f / fmaxf(sqrtf(red[0]), 1e-12f);
  dst[(size_t)row * 512 + t] = f2bf_rne(q0 * inv);
  dst[(size_t)row * 512 + t + 256] = f2bf_rne(q1 * inv);
}

// ---- candidate rescore (f64) + gather + straight-through + row loss ----
__global__ __launch_bounds__(256) void k_rescore_gather(
    const u64* __restrict__ pk, const float* __restrict__ Q,
    const float* __restrict__ z, float* __restrict__ outq,
    float* __restrict__ outidx, float* __restrict__ rloss) {
  __shared__ float sz[512];
  __shared__ double redd[8];
  __shared__ u64 redk[4];
  __shared__ int cand[64];
  __shared__ int ccount;
  const int row = blockIdx.x, t = threadIdx.x;

  sz[t] = z[(size_t)row * 512 + t];
  sz[t + 256] = z[(size_t)row * 512 + t + 256];
  if (t == 0) ccount = 0;

  u64 k1 = pk[(size_t)row * 256 + t];   // 64 chunks x 4 slots = 256 keys/row
  u64 km = k1;
  for (int m = 1; m < 64; m <<= 1)
    km = umax64(km, (u64)__shfl_xor((long long)km, m));
  if ((t & 63) == 0) redk[t >> 6] = km;
  __syncthreads();
  u64 gk = umax64(umax64(redk[0], redk[1]), umax64(redk[2], redk[3]));
  float thresh = key_val(gk) - MARGIN;

  if (key_val(k1) >= thresh) { int p = atomicAdd(&ccount, 1); if (p < 64) cand[p] = key_idx(k1); }
  __syncthreads();
  int nc = ccount < 64 ? ccount : 64;

  double bs = -1e300;
  int bi = 0x7FFFFFFF;
  for (int c = 0; c < nc; ++c) {
    int code = cand[c];
    const float* Qr = Q + (size_t)code * 512;
    double dotp = 0.0, qq = 0.0;
#pragma unroll
    for (int h = 0; h < 2; ++h) {
      int d = t + h * 256;
      double qv = (double)Qr[d];
      dotp += (double)sz[d] * qv;
      qq += qv * qv;
    }
    for (int m = 1; m < 64; m <<= 1) {
      dotp += __shfl_xor(dotp, m);
      qq += __shfl_xor(qq, m);
    }
    if ((t & 63) == 0) { redd[t >> 6] = dotp; redd[4 + (t >> 6)] = qq; }
    __syncthreads();
    double dsum = redd[0] + redd[1] + redd[2] + redd[3];
    double qsum = redd[4] + redd[5] + redd[6] + redd[7];
    double s = dsum / fmax(sqrt(qsum), 1e-12);
    if (s > bs || (s == bs && code < bi)) { bs = s; bi = code; }
    __syncthreads();
  }

  const float* Qb = Q + (size_t)bi * 512;
  double lsum = 0.0;
#pragma unroll
  for (int h = 0; h < 2; ++h) {
    int d = t + h * 256;
    float qv = Qb[d], zv = sz[d];
    outq[(size_t)row * 512 + d] = zv + (qv - zv);
    float df = qv - zv;
    lsum += (double)df * (double)df;
  }
  for (int m = 1; m < 64; m <<= 1) lsum += __shfl_xor(lsum, m);
  if ((t & 63) == 0) redd[t >> 6] = lsum;
  __syncthreads();
  if (t == 0) {
    rloss[row] = (float)(redd[0] + redd[1] + redd[2] + redd[3]);
    outidx[row] = (float)bi;
  }
}

__global__ __launch_bounds__(256) void k_loss_final(const float* __restrict__ rloss,
                                                    float* __restrict__ out_loss) {
  __shared__ float sl[256];
  int t = threadIdx.x;
  float s = 0.f;
#pragma unroll
  for (int i = 0; i < 32; ++i) s += rloss[t + i * 256];
  sl[t] = s;
  __syncthreads();
  for (int k = 128; k > 0; k >>= 1) {
    if (t < k) sl[t] += sl[t + k];
    __syncthreads();
  }
  if (t == 0) out_loss[0] = 1.25f * sl[0] / 4194304.0f;
}

extern "C" void kernel_launch(void* const* d_in, const int* in_sizes, int n_in,
                              void* d_out, int out_size, void* d_ws, size_t ws_size,
                              hipStream_t stream) {
  const float* z = (const float*)d_in[0];
  const float* emb = (const float*)d_in[1];
  const float* pw = (const float*)d_in[2];
  const float* pb = (const float*)d_in[3];

  char* ws = (char*)d_ws;
  float* Q = (float*)(ws + OFF_Q);
  f16* ehi = (f16*)(ws + OFF_EHI);
  f16* elo = (f16*)(ws + OFF_ELO);
  f16* whi = (f16*)(ws + OFF_WHI);
  f16* wlo = (f16*)(ws + OFF_WLO);
  ushort_t* cb = (ushort_t*)(ws + OFF_CB);
  ushort_t* zb = (ushort_t*)(ws + OFF_ZB);
  u64* pk = (u64*)(ws + OFF_PK);
  float* rloss = (float*)(ws + OFF_RL);

  float* outq = (float*)d_out;
  float* outloss = outq + 4194304;
  float* outidx = outq + 4194305;

  k_split<<<8192, 256, 0, stream>>>(emb, ehi, elo, 2097152);
  k_split<<<256, 256, 0, stream>>>(pw, whi, wlo, 65536);
  k_norm_bf16<<<8192, 256, 0, stream>>>(z, zb);                    // z_n bf16
  k_gemm_codebook<<<dim3(4, 128), 256, 0, stream>>>(ehi, elo, whi, wlo, pb, Q);
  k_norm_bf16<<<16384, 256, 0, stream>>>(Q, cb);                   // c_n bf16
  k_gemm_coarse8<<<dim3(64, 32), 512, 0, stream>>>(cb, zb, pk);
  k_rescore_gather<<<8192, 256, 0, stream>>>(pk, Q, z, outq, outidx, rloss);
  k_loss_final<<<1, 256, 0, stream>>>(rloss, outloss);
}

// Round 9
// 298.576 us; speedup vs baseline: 1.1817x; 1.0066x over previous
//
#include <hip/hip_runtime.h>
#include <math.h>

// ---------------------------------------------------------------------------
// SimVQ forward, round 9: faithful m201 8-phase schedule for the coarse GEMM.
//  - 1 half-tile (2 loads/thread) staged per phase, spread across all phases.
//  - vmcnt(6) ONLY at group ends (3 halves always in flight); vmcnt(0) only
//    at g==6 (tail); never a per-phase drain.
//  - quadrant phases (m0n0, m0n1, m1n1, m1n0) with A/B register reuse:
//    12/4/8/0 ds_reads per phase.
//  - interleaved wave mapping (A-top = all waves' mh0) so each half is
//    register-captured >=1 barrier before its replacement stage issues.
//  - XCD swizzle on flattened 2048-block grid (2048%8==0, bijective).
// Fallback (pre-committed): coarse8 >= 180us -> revert to round-5 coarse.
// ---------------------------------------------------------------------------

typedef _Float16 f16;
typedef _Float16 f16x8 __attribute__((ext_vector_type(8)));
typedef _Float16 f16x4 __attribute__((ext_vector_type(4)));
typedef short s16x8 __attribute__((ext_vector_type(8)));
typedef float f32x4 __attribute__((ext_vector_type(4)));
typedef unsigned int u32;
typedef unsigned long long u64;
typedef unsigned short ushort_t;

#define INV2048 (1.0f/2048.0f)
#define MARGIN  0.010f

// ---- workspace layout (bytes) ----
#define OFF_Q    0u            // 16384*512*4 = 33554432
#define OFF_EHI  33554432u     // emb hi f16 (dead after codebook GEMM)
#define OFF_ELO  50331648u     // emb lo f16 (dead after codebook GEMM)
#define OFF_WHI  67108864u     // 512*512*2
#define OFF_WLO  67633152u
#define OFF_CB   68157440u     // codebook bf16 normalized, 16384*512*2
#define OFF_ZB   84934656u     // z normalized bf16, 8192*512*2
#define OFF_RL   93323264u     // 8192*4 per-row loss
#define OFF_PK   OFF_EHI       // alias: cand keys, 8192*256*8 = 16777216

__device__ __forceinline__ void gload_lds16(const void* g, void* l) {
  __builtin_amdgcn_global_load_lds(
      (const __attribute__((address_space(1))) u32*)g,
      (__attribute__((address_space(3))) u32*)l, 16, 0, 0);
}

// ---- u64 sort keys: high 32 = ordered float, low 32 = ~idx (tie->low idx) ----
__device__ __forceinline__ u64 make_key(float v, int idx) {
  u32 b = __float_as_uint(v);
  u32 m = (u32)((int)b >> 31) | 0x80000000u;
  return ((u64)(b ^ m) << 32) | (u32)(0x7FFFFFFF - idx);
}
__device__ __forceinline__ float key_val(u64 k) {
  u32 o = (u32)(k >> 32);
  u32 m = (o & 0x80000000u) ? 0x80000000u : 0xFFFFFFFFu;
  return __uint_as_float(o ^ m);   // key 0 -> NaN (always fails >= thresh)
}
__device__ __forceinline__ int key_idx(u64 k) {
  return 0x7FFFFFFF - (int)(u32)(k & 0xFFFFFFFFu);
}
__device__ __forceinline__ u64 umax64(u64 a, u64 b) { return a > b ? a : b; }

// ======================= exact fp16 hi/lo GEMM (codebook) ====================
// (unchanged — not the bottleneck)
#define LDS_AHI 0
#define LDS_ALO 16384
#define LDS_BHI 32768
#define LDS_BLO 49152

__device__ __forceinline__ void stage_tile(const void* __restrict__ src, int row0,
                                           int kt, char* lds, int tid) {
#pragma unroll
  for (int i = 0; i < 4; ++i) {
    int lin = i * 256 + tid;
    int row = lin >> 3;
    int slot = lin & 7;
    int k8 = slot ^ (row & 7);
    const char* g = (const char*)src + (((size_t)(row0 + row)) << 10)
                    + (size_t)(kt * 128 + k8 * 16);
    gload_lds16(g, lds + lin * 16);
  }
}

__global__ __launch_bounds__(256, 2) void k_gemm_codebook(
    const f16* __restrict__ Ahi, const f16* __restrict__ Alo,
    const f16* __restrict__ Bhi, const f16* __restrict__ Blo,
    const float* __restrict__ bias, float* __restrict__ Q) {
  __shared__ __align__(16) char lds[65536];
  f32x4 hh[4][4], xx[4][4];
  const int tid = threadIdx.x;
  const int m0 = blockIdx.y * 128;
  const int n0 = blockIdx.x * 128;
  const int l = tid & 63;
  const int wid = tid >> 6;
  const int wr = (wid >> 1) * 64;
  const int wc = (wid & 1) * 64;
  const int r7 = (l & 15) & 7;

#pragma unroll
  for (int a = 0; a < 4; ++a)
#pragma unroll
    for (int b = 0; b < 4; ++b) {
      hh[a][b] = (f32x4){0.f, 0.f, 0.f, 0.f};
      xx[a][b] = (f32x4){0.f, 0.f, 0.f, 0.f};
    }

  for (int kt = 0; kt < 8; ++kt) {
    stage_tile(Ahi, m0, kt, lds + LDS_AHI, tid);
    stage_tile(Alo, m0, kt, lds + LDS_ALO, tid);
    stage_tile(Bhi, n0, kt, lds + LDS_BHI, tid);
    stage_tile(Blo, n0, kt, lds + LDS_BLO, tid);
    __syncthreads();
#pragma unroll
    for (int ks = 0; ks < 2; ++ks) {
      const int kg = ks * 4 + (l >> 4);
      const int s = (kg ^ r7) * 16;
      const char* pa = lds + (wr + (l & 15)) * 128 + s;
      const char* pb = lds + (wc + (l & 15)) * 128 + s;
      f16x8 ahi[4], alo[4];
#pragma unroll
      for (int mf = 0; mf < 4; ++mf) {
        ahi[mf] = *(const f16x8*)(pa + LDS_AHI + mf * 2048);
        alo[mf] = *(const f16x8*)(pa + LDS_ALO + mf * 2048);
      }
#pragma unroll
      for (int nf = 0; nf < 4; ++nf) {
        f16x8 bhi = *(const f16x8*)(pb + LDS_BHI + nf * 2048);
        f16x8 blo = *(const f16x8*)(pb + LDS_BLO + nf * 2048);
#pragma unroll
        for (int mf = 0; mf < 4; ++mf) {
          hh[mf][nf] = __builtin_amdgcn_mfma_f32_16x16x32_f16(ahi[mf], bhi, hh[mf][nf], 0, 0, 0);
          xx[mf][nf] = __builtin_amdgcn_mfma_f32_16x16x32_f16(ahi[mf], blo, xx[mf][nf], 0, 0, 0);
          xx[mf][nf] = __builtin_amdgcn_mfma_f32_16x16x32_f16(alo[mf], bhi, xx[mf][nf], 0, 0, 0);
        }
      }
    }
    __syncthreads();
  }

#pragma unroll
  for (int mf = 0; mf < 4; ++mf)
#pragma unroll
    for (int nf = 0; nf < 4; ++nf)
#pragma unroll
      for (int j = 0; j < 4; ++j) {
        int row = m0 + wr + mf * 16 + (l >> 4) * 4 + j;
        int col = n0 + wc + nf * 16 + (l & 15);
        Q[(size_t)row * 512 + col] = hh[mf][nf][j] + xx[mf][nf][j] * INV2048 + bias[col];
      }
}

// ================= faithful 8-phase 256x256 bf16 coarse GEMM =================
// A = codebook bf16 [16384][512], B = z_n bf16 [8192][512]. C[code][z].
// LDS buf c at c*65536: A rows 0..255 x 128B @+0, B cols 0..255 x 128B @+32768.
// Row layout: phys slot s of row r holds logical k-chunk s ^ (r&7).
// Interleaved mapping: A row = mh*128 + wr*64 + mfi*16 + (l&15);
//                      B col = nh*128 + wc*32 + nfi*16 + (l&15).
// Halves: hw 0=A[0:128] 1=A[128:256] 2=B[0:128] 3=B[128:256] (16KB each).
// Stage stream per group g: i0: (g+1,hw1) | i1: (g+2,hw0) | i2: (g+2,hw2)
//                          | i3: (g+2,hw3). Waits: vmcnt(6) end-g (g<6),
//                          vmcnt(0) at g==6, none at g==7.
#define BAR() __builtin_amdgcn_s_barrier()

#define STAGE_HALF(TT, HW)                                                     \
  {                                                                            \
    const char* g0_ = (((HW) >> 1) ? srcZ : srcC)                              \
                      + (((HW) & 1) ? 131072 : 0) + (TT) * 128;                \
    char* d0_ = lds + ((TT) & 1) * 65536 + ((HW) >> 1) * 32768                 \
                + ((HW) & 1) * 16384;                                          \
    gload_lds16(g0_ + goff0, d0_ + doff0);                                     \
    gload_lds16(g0_ + goff1, d0_ + doff1);                                     \
  }

#define LDA(MH)                                                                \
  _Pragma("unroll") for (int mfi_ = 0; mfi_ < 4; ++mfi_) {                     \
    a[mfi_][0] = *(const s16x8*)(lds + buf + abase + (MH) * 16384 + mfi_ * 2048 + sk0); \
    a[mfi_][1] = *(const s16x8*)(lds + buf + abase + (MH) * 16384 + mfi_ * 2048 + sk1); \
  }
#define LDB(NH)                                                                \
  _Pragma("unroll") for (int nfi_ = 0; nfi_ < 2; ++nfi_) {                     \
    b[NH][nfi_][0] = *(const s16x8*)(lds + buf + bbase + (NH) * 16384 + nfi_ * 2048 + sk0); \
    b[NH][nfi_][1] = *(const s16x8*)(lds + buf + bbase + (NH) * 16384 + nfi_ * 2048 + sk1); \
  }

#define MM(AB, NH)                                                             \
  __builtin_amdgcn_s_setprio(1);                                               \
  _Pragma("unroll") for (int nfi_ = 0; nfi_ < 2; ++nfi_)                       \
  _Pragma("unroll") for (int mfi_ = 0; mfi_ < 4; ++mfi_) {                     \
    acc[(AB) + mfi_][(NH) * 2 + nfi_] = __builtin_amdgcn_mfma_f32_16x16x32_bf16( \
        a[mfi_][0], b[NH][nfi_][0], acc[(AB) + mfi_][(NH) * 2 + nfi_], 0, 0, 0); \
    acc[(AB) + mfi_][(NH) * 2 + nfi_] = __builtin_amdgcn_mfma_f32_16x16x32_bf16( \
        a[mfi_][1], b[NH][nfi_][1], acc[(AB) + mfi_][(NH) * 2 + nfi_], 0, 0, 0); \
  }                                                                            \
  __builtin_amdgcn_s_setprio(0);

__global__ __launch_bounds__(512, 2) void k_gemm_coarse8(
    const ushort_t* __restrict__ CB, const ushort_t* __restrict__ ZB,
    u64* __restrict__ pk) {
  __shared__ __align__(16) char lds[131072];
  const int tid = threadIdx.x;
  const int l = tid & 63;
  const int wid = tid >> 6;
  const int wr = wid >> 2;        // 0..1
  const int wc = wid & 3;         // 0..3
  // XCD swizzle (bijective: 2048 % 8 == 0)
  const int id = blockIdx.x;
  const int swz = (id & 7) * 256 + (id >> 3);
  const int cbx = swz & 63, zby = swz >> 6;
  const int cb0 = cbx * 256, zb0 = zby * 256;

  // staging constants (2 chunks per thread per half)
  const int lin0 = wid * 128 + l;
  const int lin1 = lin0 + 64;
  const u32 goff0 = (u32)((lin0 >> 3) * 1024 + (((lin0 & 7) ^ ((lin0 >> 3) & 7)) * 16));
  const u32 goff1 = (u32)((lin1 >> 3) * 1024 + (((lin1 & 7) ^ ((lin1 >> 3) & 7)) * 16));
  const u32 doff0 = (u32)lin0 * 16;
  const u32 doff1 = (u32)lin1 * 16;
  const char* srcC = (const char*)CB + ((size_t)cb0 << 10);
  const char* srcZ = (const char*)ZB + ((size_t)zb0 << 10);

  // fragment-read constants
  const int r7 = l & 7;
  const u32 sk0 = (u32)(((l >> 4) ^ r7) * 16);
  const u32 sk1 = (u32)((((l >> 4) | 4) ^ r7) * 16);
  const u32 abase = (u32)(wr * 8192 + (l & 15) * 128);           // + mh*16384 + mfi*2048
  const u32 bbase = (u32)(32768 + wc * 4096 + (l & 15) * 128);   // + nh*16384 + nfi*2048

  f32x4 acc[8][4];
#pragma unroll
  for (int x = 0; x < 8; ++x)
#pragma unroll
    for (int y = 0; y < 4; ++y) acc[x][y] = (f32x4){0.f, 0.f, 0.f, 0.f};
  s16x8 a[4][2];
  s16x8 b[2][2][2];

  // prologue: T0 all 4 halves + T1 {hw0, hw2, hw3}; vmcnt(6) retires T0.
  STAGE_HALF(0, 0) STAGE_HALF(0, 1) STAGE_HALF(0, 2) STAGE_HALF(0, 3)
  STAGE_HALF(1, 0) STAGE_HALF(1, 2) STAGE_HALF(1, 3)
  asm volatile("s_waitcnt vmcnt(6)" ::: "memory");
  BAR();

#pragma unroll
  for (int g = 0; g < 8; ++g) {
    const u32 buf = (u32)(g & 1) * 65536u;
    // ---- i0: (mh0, nh0) — 12 ds_reads; stage (g+1, A-bot) ----
    LDA(0) LDB(0)
    if (g < 7) STAGE_HALF(g + 1, 1)
    BAR();
    MM(0, 0)
    BAR();
    // ---- i1: (mh0, nh1) — 4 ds_reads; stage (g+2, A-top) ----
    LDB(1)
    if (g < 6) STAGE_HALF(g + 2, 0)
    BAR();
    MM(0, 1)
    BAR();
    // ---- i2: (mh1, nh1) — 8 ds_reads; stage (g+2, B-top) ----
    LDA(1)
    if (g < 6) STAGE_HALF(g + 2, 2)
    BAR();
    MM(4, 1)
    BAR();
    // ---- i3: (mh1, nh0) — 0 ds_reads; stage (g+2, B-bot); boundary wait ----
    if (g < 6) STAGE_HALF(g + 2, 3)
    BAR();
    MM(4, 0)
    if (g < 6) { asm volatile("s_waitcnt vmcnt(6)" ::: "memory"); }
    else if (g == 6) { asm volatile("s_waitcnt vmcnt(0)" ::: "memory"); }
    BAR();
  }
  __syncthreads();

  // ---- epilogue: chunk-max + within-margin collect over 256 codes ----
  // acc[A][N][j]: code = cb0 + (A>>2)*128 + wr*64 + (A&3)*16 + (l>>4)*4 + j
  //              col  = (N>>1)*128 + wc*32 + (N&1)*16 + (l&15)
  float* cmax = (float*)lds;            // [256 cols][2 wr]
  u32* cnt = (u32*)(lds + 2048);        // [256]
  u64* slots = (u64*)(lds + 4096);      // [256][4]

  float cm[4];
#pragma unroll
  for (int N = 0; N < 4; ++N) {
    float m = acc[0][N][0];
#pragma unroll
    for (int A = 0; A < 8; ++A)
#pragma unroll
      for (int j = 0; j < 4; ++j) m = fmaxf(m, acc[A][N][j]);
    m = fmaxf(m, __shfl_xor(m, 16, 64));
    m = fmaxf(m, __shfl_xor(m, 32, 64));
    cm[N] = m;
  }
  if (tid < 256) cnt[tid] = 0;
  slots[tid] = 0;
  slots[tid + 512] = 0;
  if ((l >> 4) == 0) {
#pragma unroll
    for (int N = 0; N < 4; ++N)
      cmax[((N >> 1) * 128 + wc * 32 + (N & 1) * 16 + l) * 2 + wr] = cm[N];
  }
  __syncthreads();

#pragma unroll
  for (int N = 0; N < 4; ++N) {
    int col = (N >> 1) * 128 + wc * 32 + (N & 1) * 16 + (l & 15);
    float thresh = fmaxf(cmax[col * 2], cmax[col * 2 + 1]) - MARGIN;
#pragma unroll
    for (int A = 0; A < 8; ++A)
#pragma unroll
      for (int j = 0; j < 4; ++j) {
        float v = acc[A][N][j];
        if (v >= thresh) {
          int code = cb0 + (A >> 2) * 128 + wr * 64 + (A & 3) * 16 + ((l >> 4) << 2) + j;
          u32 p = atomicAdd(&cnt[col], 1u);
          if (p < 4) slots[col * 4 + p] = make_key(v, code);
        }
      }
  }
  __syncthreads();

  if (tid < 256) {
    size_t base = (((size_t)(zb0 + tid)) * 64 + cbx) * 4;
#pragma unroll
    for (int s = 0; s < 4; ++s) pk[base + s] = slots[tid * 4 + s];
  }
}

// ---- f32 -> fp16 hi/lo split ----
__global__ __launch_bounds__(256) void k_split(const float* __restrict__ src,
                                               f16* __restrict__ hi,
                                               f16* __restrict__ lo, int n4) {
  int i = blockIdx.x * 256 + threadIdx.x;
  if (i >= n4) return;
  const float4 v = ((const float4*)src)[i];
  f16 h0 = (f16)v.x, h1 = (f16)v.y, h2 = (f16)v.z, h3 = (f16)v.w;
  ((f16x4*)hi)[i] = (f16x4){h0, h1, h2, h3};
  ((f16x4*)lo)[i] = (f16x4){(f16)((v.x - (float)h0) * 2048.0f),
                            (f16)((v.y - (float)h1) * 2048.0f),
                            (f16)((v.z - (float)h2) * 2048.0f),
                            (f16)((v.w - (float)h3) * 2048.0f)};
}

__device__ __forceinline__ ushort_t f2bf_rne(float f) {
  u32 b = __float_as_uint(f);
  b += 0x7FFFu + ((b >> 16) & 1u);
  return (ushort_t)(b >> 16);
}

// ---- row L2-normalize src -> bf16 dst. One block per row, 512 cols ----
__global__ __launch_bounds__(256) void k_norm_bf16(const float* __restrict__ src,
                                                   ushort_t* __restrict__ dst) {
  __shared__ float red[256];
  const int row = blockIdx.x, t = threadIdx.x;
  float q0 = src[(size_t)row * 512 + t];
  float q1 = src[(size_t)row * 512 + t + 256];
  red[t] = q0 * q0 + q1 * q1;
  __syncthreads();
  for (int s = 128; s > 0; s >>= 1) {
    if (t < s) red[t] += red[t + s];
    __syncthreads();
  }
  float inv = 1.0f / fmaxf(sqrtf(red[0]), 1e-12f);
  dst[(size_t)row * 512 + t] = f2bf_rne(q0 * inv);
  dst[(size_t)row * 512 + t + 256] = f2bf_rne(q1 * inv);
}

// ---- candidate rescore (f64) + gather + straight-through + row loss ----
__global__ __launch_bounds__(256) void k_rescore_gather(
    const u64* __restrict__ pk, const float* __restrict__ Q,
    const float* __restrict__ z, float* __restrict__ outq,
    float* __restrict__ outidx, float* __restrict__ rloss) {
  __shared__ float sz[512];
  __shared__ double redd[8];
  __shared__ u64 redk[4];
  __shared__ int cand[64];
  __shared__ int ccount;
  const int row = blockIdx.x, t = threadIdx.x;

  sz[t] = z[(size_t)row * 512 + t];
  sz[t + 256] = z[(size_t)row * 512 + t + 256];
  if (t == 0) ccount = 0;

  u64 k1 = pk[(size_t)row * 256 + t];   // 64 chunks x 4 slots = 256 keys/row
  u64 km = k1;
  for (int m = 1; m < 64; m <<= 1)
    km = umax64(km, (u64)__shfl_xor((long long)km, m));
  if ((t & 63) == 0) redk[t >> 6] = km;
  __syncthreads();
  u64 gk = umax64(umax64(redk[0], redk[1]), umax64(redk[2], redk[3]));
  float thresh = key_val(gk) - MARGIN;

  if (key_val(k1) >= thresh) { int p = atomicAdd(&ccount, 1); if (p < 64) cand[p] = key_idx(k1); }
  __syncthreads();
  int nc = ccount < 64 ? ccount : 64;

  double bs = -1e300;
  int bi = 0x7FFFFFFF;
  for (int c = 0; c < nc; ++c) {
    int code = cand[c];
    const float* Qr = Q + (size_t)code * 512;
    double dotp = 0.0, qq = 0.0;
#pragma unroll
    for (int h = 0; h < 2; ++h) {
      int d = t + h * 256;
      double qv = (double)Qr[d];
      dotp += (double)sz[d] * qv;
      qq += qv * qv;
    }
    for (int m = 1; m < 64; m <<= 1) {
      dotp += __shfl_xor(dotp, m);
      qq += __shfl_xor(qq, m);
    }
    if ((t & 63) == 0) { redd[t >> 6] = dotp; redd[4 + (t >> 6)] = qq; }
    __syncthreads();
    double dsum = redd[0] + redd[1] + redd[2] + redd[3];
    double qsum = redd[4] + redd[5] + redd[6] + redd[7];
    double s = dsum / fmax(sqrt(qsum), 1e-12);
    if (s > bs || (s == bs && code < bi)) { bs = s; bi = code; }
    __syncthreads();
  }

  const float* Qb = Q + (size_t)bi * 512;
  double lsum = 0.0;
#pragma unroll
  for (int h = 0; h < 2; ++h) {
    int d = t + h * 256;
    float qv = Qb[d], zv = sz[d];
    outq[(size_t)row * 512 + d] = zv + (qv - zv);
    float df = qv - zv;
    lsum += (double)df * (double)df;
  }
  for (int m = 1; m < 64; m <<= 1) lsum += __shfl_xor(lsum, m);
  if ((t & 63) == 0) redd[t >> 6] = lsum;
  __syncthreads();
  if (t == 0) {
    rloss[row] = (float)(redd[0] + redd[1] + redd[2] + redd[3]);
    outidx[row] = (float)bi;
  }
}

__global__ __launch_bounds__(256) void k_loss_final(const float* __restrict__ rloss,
                                                    float* __restrict__ out_loss) {
  __shared__ float sl[256];
  int t = threadIdx.x;
  float s = 0.f;
#pragma unroll
  for (int i = 0; i < 32; ++i) s += rloss[t + i * 256];
  sl[t] = s;
  __syncthreads();
  for (int k = 128; k > 0; k >>= 1) {
    if (t < k) sl[t] += sl[t + k];
    __syncthreads();
  }
  if (t == 0) out_loss[0] = 1.25f * sl[0] / 4194304.0f;
}

extern "C" void kernel_launch(void* const* d_in, const int* in_sizes, int n_in,
                              void* d_out, int out_size, void* d_ws, size_t ws_size,
                              hipStream_t stream) {
  const float* z = (const float*)d_in[0];
  const float* emb = (const float*)d_in[1];
  const float* pw = (const float*)d_in[2];
  const float* pb = (const float*)d_in[3];

  char* ws = (char*)d_ws;
  float* Q = (float*)(ws + OFF_Q);
  f16* ehi = (f16*)(ws + OFF_EHI);
  f16* elo = (f16*)(ws + OFF_ELO);
  f16* whi = (f16*)(ws + OFF_WHI);
  f16* wlo = (f16*)(ws + OFF_WLO);
  ushort_t* cb = (ushort_t*)(ws + OFF_CB);
  ushort_t* zb = (ushort_t*)(ws + OFF_ZB);
  u64* pk = (u64*)(ws + OFF_PK);
  float* rloss = (float*)(ws + OFF_RL);

  float* outq = (float*)d_out;
  float* outloss = outq + 4194304;
  float* outidx = outq + 4194305;

  k_split<<<8192, 256, 0, stream>>>(emb, ehi, elo, 2097152);
  k_split<<<256, 256, 0, stream>>>(pw, whi, wlo, 65536);
  k_norm_bf16<<<8192, 256, 0, stream>>>(z, zb);                    // z_n bf16
  k_gemm_codebook<<<dim3(4, 128), 256, 0, stream>>>(ehi, elo, whi, wlo, pb, Q);
  k_norm_bf16<<<16384, 256, 0, stream>>>(Q, cb);                   // c_n bf16
  k_gemm_coarse8<<<2048, 512, 0, stream>>>(cb, zb, pk);
  k_rescore_gather<<<8192, 256, 0, stream>>>(pk, Q, z, outq, outidx, rloss);
  k_loss_final<<<1, 256, 0, stream>>>(rloss, outloss);
}